// Round 10
// baseline (2183.909 us; speedup 1.0000x reference)
//
#include <hip/hip_runtime.h>
#include <hip/hip_bf16.h>

#define BB 32
#define SS 160
#define KK 44
#define EE 300
#define HH 256
#define VV 32000
#define G3 768
#define EHP 576
#define EP  320
#define NSEQ 5120
#define NROW 10240
#define NKEY 20480

typedef unsigned short u16;
typedef unsigned char u8;
typedef long i64;
typedef __attribute__((ext_vector_type(8))) short bf16x8;
typedef __attribute__((ext_vector_type(4))) float f32x4;
typedef __attribute__((ext_vector_type(2))) float f32x2;
typedef __attribute__((ext_vector_type(4))) int i32x4;

static __device__ __forceinline__ u16 f2bf(float f) {
  union { float f; unsigned u; } x; x.f = f;
  unsigned u = x.u;
  unsigned r = (u + 0x7fffu + ((u >> 16) & 1u)) >> 16;
  return (u16)r;
}
static __device__ __forceinline__ float bf2f(u16 v) {
  union { unsigned u; float f; } x; x.u = ((unsigned)v) << 16;
  return x.f;
}
static __device__ __forceinline__ u8 ftofp8(float v) {
  return (u8)(__builtin_amdgcn_cvt_pk_fp8_f32(v, v, 0, false) & 0xff);
}
static __device__ __forceinline__ float fsig(float x) {
  float e = __expf(-x);
  return __builtin_amdgcn_rcpf(1.f + e);
}
static __device__ __forceinline__ float ftanh(float x) {
  float e = __expf(2.f * x);
  return 1.f - 2.f * __builtin_amdgcn_rcpf(1.f + e);
}

// fp32 (rows,K) -> bf16 (rows,ldp), zero pad cols K..ldp
__global__ void cvt_pad(const float* __restrict__ src, u16* __restrict__ dst,
                        int rows, int K, int ldp) {
  int idx = blockIdx.x * blockDim.x + threadIdx.x;
  int tot = rows * ldp;
  if (idx >= tot) return;
  int c = idx % ldp; int r = idx / ldp;
  float v = (c < K) ? src[(size_t)r * K + c] : 0.f;
  dst[idx] = f2bf(v);
}

// fp32 -> fp8 e4m3, flat
__global__ void cvt_f8(const float* __restrict__ src, u8* __restrict__ dst, int n) {
  int i = blockIdx.x * blockDim.x + threadIdx.x;
  if (i < n) dst[i] = ftofp8(src[i]);
}

// o[j] = bi[j] + (j<512 ? bh[j] : 0)
__global__ void bias_comb(const float* __restrict__ bi, const float* __restrict__ bh,
                          float* __restrict__ o) {
  int j = blockIdx.x * blockDim.x + threadIdx.x;
  if (j >= G3) return;
  o[j] = bi[j] + (j < 512 ? bh[j] : 0.f);
}

// C = A @ B^T + bias; 2 row-tiles x 4 col-tiles per wave.
// Output modes: C fp32 | Cbf bf16 | C8 = packed key-table rows:
//   row = 1024B: bytes[2c]=r-fp8, bytes[2c+1]=z-fp8, bytes[512+2c..]=n-bf16.
__global__ void gemm_bt24(const u16* __restrict__ A, const u16* __restrict__ B,
                          float* __restrict__ C, u16* __restrict__ Cbf,
                          u8* __restrict__ C8,
                          const float* __restrict__ bias,
                          int M, int N, int K, int lda, int ldb, int ldc) {
  int gid = blockIdx.x * blockDim.x + threadIdx.x;
  int wid = gid >> 6, lane = gid & 63;
  int ntg = N >> 6;
  int total = (M >> 5) * ntg;
  if (wid >= total) return;
  int tm = wid / ntg, tg = wid - tm * ntg;
  int rbase = tm << 5, cbase = tg << 6;
  int m = lane & 15, quad = lane >> 4;
  const u16* ap0 = A + (size_t)(rbase + m) * lda + quad * 8;
  const u16* ap1 = ap0 + (size_t)16 * lda;
  const u16* bp0 = B + (size_t)(cbase + m) * ldb + quad * 8;
  f32x4 acc[2][4];
  #pragma unroll
  for (int r = 0; r < 2; ++r)
    #pragma unroll
    for (int c = 0; c < 4; ++c) acc[r][c] = (f32x4){0.f, 0.f, 0.f, 0.f};
  for (int k = 0; k < K; k += 32) {
    bf16x8 a0 = *(const bf16x8*)(ap0 + k);
    bf16x8 a1 = *(const bf16x8*)(ap1 + k);
    #pragma unroll
    for (int c = 0; c < 4; ++c) {
      bf16x8 bv = *(const bf16x8*)(bp0 + (size_t)c * 16 * ldb + k);
      acc[0][c] = __builtin_amdgcn_mfma_f32_16x16x32_bf16(a0, bv, acc[0][c], 0, 0, 0);
      acc[1][c] = __builtin_amdgcn_mfma_f32_16x16x32_bf16(a1, bv, acc[1][c], 0, 0, 0);
    }
  }
  #pragma unroll
  for (int c = 0; c < 4; ++c) {
    int col = cbase + c * 16 + m;
    float bv = bias ? bias[col] : 0.f;
    int g = col >> 8, cc = col & 255;   // gate / in-gate col (C8 mode)
    #pragma unroll
    for (int rt = 0; rt < 2; ++rt) {
      int orow = rbase + rt * 16 + quad * 4;
      #pragma unroll
      for (int i = 0; i < 4; ++i) {
        float v = acc[rt][c][i] + bv;
        if (C8) {
          size_t rb = (size_t)(orow + i) * 1024;
          if (g < 2) C8[rb + 2 * cc + g] = ftofp8(v);
          else *(u16*)&C8[rb + 512 + 2 * cc] = f2bf(v);
        } else if (Cbf) Cbf[(size_t)(orow + i) * ldc + col] = f2bf(v);
        else C[(size_t)(orow + i) * ldc + col] = v;
      }
    }
  }
}

// Async global->LDS 16B gather; aux=0 (policy bits proved irrelevant r8/r10)
#define GLD16(gsrc, ldst)                                                     \
  __builtin_amdgcn_global_load_lds(                                           \
      (const __attribute__((address_space(1))) void*)(gsrc),                  \
      (__attribute__((address_space(3))) void*)(ldst), 16, 0, 0)

// ---- Persistent key-GRU v16 (unchanged from R9's winner): W-in-regs,
// depth-5 counted-vmcnt gather, 6-slot rotating giL, 6 barriers + 1 drain
// per step. key_gru dropped below main_gru in the R9 profile. ----
__global__ __launch_bounds__(1024) void key_gru16(
    const u8* __restrict__ W8f, const u8* __restrict__ W8b,
    const float* __restrict__ nbf, const float* __restrict__ nbb,
    const u8* __restrict__ T8F, const u8* __restrict__ T8B,
    const int* __restrict__ keys_c, const int* __restrict__ keys_r,
    float* __restrict__ h_out) {
  __shared__ __align__(16) u8 hb8[2][80 * 256];  // 2x20 KB ping-pong fp8 h
  __shared__ __align__(16) u8 giL[6 * 16384];    // 96 KB, 6 rotating slots
  __shared__ int tokL[80 * KK];                  // 14 KB token slice
  int b = blockIdx.x;
  int xcd = b & 7, slot0 = b >> 3;
  int bwd = xcd >> 2;
  int j = slot0 * 4 + (xcd & 3);
  int isR = j >> 6;
  int seq0 = (j & 63) * 80;
  const u8* W8 = bwd ? W8b : W8f;
  const u8* T = bwd ? T8B : T8F;
  const int* keys = isR ? keys_r : keys_c;
  const float* nb = bwd ? nbb : nbf;

  int tid = threadIdx.x;
  int w = tid >> 6, lane = tid & 63, m = lane & 15, quad = lane >> 4;
  int c = w * 16 + m;               // this thread's output column (0..255)
  float nbv = nb[512 + c];

  // Token slice: contiguous copy keys[seq0*KK .. (seq0+80)*KK) -> LDS.
  for (int i = tid; i < 80 * KK; i += 1024)
    tokL[i] = keys[seq0 * KK + i];

  // Whh in registers: same 192B per thread for the whole kernel.
  i64 w_r[8], w_z[8], w_n[8];
  {
    const u8* br = W8 + (size_t)(0 * 256 + c) * 256 + quad * 8;
    const u8* bz = W8 + (size_t)(1 * 256 + c) * 256 + quad * 8;
    const u8* bn = W8 + (size_t)(2 * 256 + c) * 256 + quad * 8;
    #pragma unroll
    for (int kc = 0; kc < 8; ++kc) {
      w_r[kc] = *(const i64*)(br + kc * 32);
      w_z[kc] = *(const i64*)(bz + kc * 32);
      w_n[kc] = *(const i64*)(bn + kc * 32);
    }
  }

  // Group g rows [g*16, g*16+16): one 1-row-per-wave GLD16 into slot `sl`.
  auto dma_grp = [&](int tt, int g, int sl) {
    int row = g * 16 + w;
    int tok = tokL[row * KK + tt];                   // wave-uniform ds_read
    const u8* src = T + (size_t)tok * 1024 + lane * 16;
    u8* dst = giL + sl * 16384 + w * 1024;           // + lane*16B by HW
    GLD16(src, dst);
  };

  for (int i = tid * 16; i < 80 * 256; i += 1024 * 16)
    *(i32x4*)&hb8[0][i] = (i32x4){0, 0, 0, 0};
  float h[5][4];
  #pragma unroll
  for (int rt = 0; rt < 5; ++rt)
    #pragma unroll
    for (int i = 0; i < 4; ++i) h[rt][i] = 0.f;

  // Drain ALL prologue vmem so the in-loop per-thread vmcnt stream is exactly
  // the 5 GLD16s/step; tokL + hb8 zeros visible before any dma_grp reads.
  asm volatile("s_waitcnt vmcnt(0) lgkmcnt(0)" ::: "memory");
  __builtin_amdgcn_s_barrier();

  {
    int t0 = bwd ? (KK - 1) : 0;
    #pragma unroll
    for (int g = 0; g < 5; ++g) dma_grp(t0, g, g);   // FIFO: grp0..grp4
  }

  int cc = c >> 3, lo = c & 7;
  int sb = 0;   // slot base: slot(t,g) = (g + sb) % 6; sb(t) = (-t) mod 6

  for (int step = 0; step < KK; ++step) {
    const u8* cur = hb8[step & 1];
    u8* nxt = hb8[(step & 1) ^ 1];
    int tnext = bwd ? (KK - 2 - step) : (step + 1);
    int tclamp = tnext < 0 ? 0 : (tnext > KK - 1 ? KK - 1 : tnext);  // dummy on last step

    #pragma unroll
    for (int rt = 0; rt < 5; ++rt) {
      // ---- GEMM(rt): reads only hb8 rows rt*16..rt*16+15 of cur ----
      f32x4 acc[3];
      #pragma unroll
      for (int g = 0; g < 3; ++g) acc[g] = (f32x4){0.f, 0.f, 0.f, 0.f};
      int arow = rt * 16 + m;
      #pragma unroll
      for (int kc = 0; kc < 8; ++kc) {
        i64 a = *(const i64*)&cur[arow * 256 + (((quad + 4 * kc) ^ (arow & 31)) * 8)];
        acc[0] = __builtin_amdgcn_mfma_f32_16x16x32_fp8_fp8(a, w_r[kc], acc[0], 0, 0, 0);
        acc[1] = __builtin_amdgcn_mfma_f32_16x16x32_fp8_fp8(a, w_z[kc], acc[1], 0, 0, 0);
        acc[2] = __builtin_amdgcn_mfma_f32_16x16x32_fp8_fp8(a, w_n[kc], acc[2], 0, 0, 0);
      }

      // ---- retire exactly group rt(t); keep 4 gathers in flight.
      // Also certifies all waves completed update(rt-1) -> its slot is free.
      asm volatile("s_waitcnt vmcnt(4)" ::: "memory");
      __builtin_amdgcn_s_barrier();
      __builtin_amdgcn_sched_barrier(0);

      // ---- update(rt): reads giL slot(t,rt), writes nxt rows rt ----
      const u16* giU = (const u16*)(giL + ((rt + sb) % 6) * 16384);
      #pragma unroll
      for (int i = 0; i < 4; ++i) {
        int lrow = quad * 4 + i;
        int row = rt * 16 + lrow;
        u16 vrz = giU[lrow * 512 + c];
        f32x2 grz = __builtin_amdgcn_cvt_pk_f32_fp8((int)vrz, false);
        float gn = bf2f(giU[lrow * 512 + 256 + c]);
        float rr = fsig(grz[0] + acc[0][i]);
        float zz = fsig(grz[1] + acc[1][i]);
        float nn = ftanh(gn + rr * (acc[2][i] + nbv));
        float hv = (1.f - zz) * nn + zz * h[rt][i];
        h[rt][i] = hv;
        nxt[row * 256 + ((cc ^ (row & 31)) * 8) + lo] = ftofp8(hv);
      }
      __builtin_amdgcn_sched_barrier(0);  // cap live range per rt-group
      // dma group rt(t+1) into slot(t+1,rt) = slot(t,rt-1) (rt=0 -> free slot)
      dma_grp(tclamp, rt, (rt + sb + 5) % 6);
    }

    // ---- step end: hb8[nxt] writes visible to all waves' next GEMM ----
    asm volatile("s_waitcnt lgkmcnt(0)" ::: "memory");
    __builtin_amdgcn_s_barrier();
    sb = (sb + 5) % 6;
  }

  // Coalesced fp32 epilogue via giL staging (drains dummy DMAs first)
  __syncthreads();
  float* hstage = (float*)giL;
  #pragma unroll
  for (int rt = 0; rt < 5; ++rt)
    #pragma unroll
    for (int i = 0; i < 4; ++i)
      hstage[(rt * 16 + quad * 4 + i) * 256 + c] = h[rt][i];
  __syncthreads();
  size_t rowbase = (size_t)(bwd * NROW + isR * NSEQ + seq0) * 256;
  for (int i = tid * 4; i < 80 * 256; i += 1024 * 4)
    *(f32x4*)&h_out[rowbase + i] = *(const f32x4*)&hstage[i];
}

// Build concat inputs for the main GRU, bf16 padded.
__global__ void build_xe(const float* __restrict__ emb, const int* __restrict__ x1,
                         const int* __restrict__ x2, const float* __restrict__ hk,
                         u16* __restrict__ xe) {
  int idx = blockIdx.x * blockDim.x + threadIdx.x;
  if (idx >= NROW * EHP) return;
  int c = idx % EHP; int rr = idx / EHP;
  int isX2 = rr >= NSEQ;
  int seq = rr - (isX2 ? NSEQ : 0);
  float v;
  if (c < EE) {
    int tok = (isX2 ? x2 : x1)[seq];
    v = emb[(size_t)tok * EE + c];
  } else if (c < EE + HH) {
    int j = c - EE;
    int frow = (isX2 ? NSEQ : 0) + seq;
    v = hk[(size_t)frow * HH + j] + hk[(size_t)(NROW + frow) * HH + j];
  } else {
    v = 0.f;
  }
  xe[idx] = f2bf(v);
}

// ---- Persistent main GRU v5: 8 blocks x 1024 threads, ping-pong h buffer,
// ONE barrier per step + REGISTER PREFETCH of gi(t+1).
// R9 profile: main_gru4 = 735us at 1.4% occupancy, 68 GB/s, 0.43% MfmaUtil
// -- each step serially exposed the HBM/L2 latency of its 12 gi loads
// (4.6us/step for ~0.6us of work; 8 blocks = no TLP to hide it). gi
// addresses depend only on `step`, not on the recurrence -> issue step
// t+1's loads BEFORE step t's GEMM; their waitcnt lands at the copy after
// the barrier, giving a full step of overlap. +12 VGPR on a 64-VGPR
// kernel. Math unchanged.
__global__ __launch_bounds__(1024, 1) void main_gru5(
    const u16* __restrict__ Wf, const u16* __restrict__ Wb,
    const float* __restrict__ nbf, const float* __restrict__ nbb,
    const float* __restrict__ Gf, const float* __restrict__ Gb,
    float* __restrict__ sc, u16* __restrict__ scbf,
    float* __restrict__ rvec, u16* __restrict__ rbf) {
  __shared__ __align__(16) u16 hbuf[2][16 * 256];
  int rt = blockIdx.x;
  int q = rt >> 1;
  int bwd = q >> 1, isX2 = q & 1;
  const u16* W = bwd ? Wb : Wf;
  const float* G = bwd ? Gb : Gf;
  const float* nb = bwd ? nbb : nbf;
  int tid = threadIdx.x, w = tid >> 6, lane = tid & 63, m = lane & 15, quad = lane >> 4;
  int c = w * 16 + m;
  float nbv = nb[512 + c];

  const u16* bp[3];
  #pragma unroll
  for (int g = 0; g < 3; ++g)
    bp[g] = W + (size_t)(g * 256 + c) * 256 + quad * 8;

  auto load_gi = [&](int s, float (&gg)[3][4]) {
    #pragma unroll
    for (int i = 0; i < 4; ++i) {
      int bb = ((rt & 1) << 4) + quad * 4 + i;
      size_t girow = ((size_t)(isX2 * NSEQ + bb * SS + s)) * G3;
      #pragma unroll
      for (int g = 0; g < 3; ++g)
        gg[g][i] = G[girow + g * 256 + c];
    }
  };

  for (int i = tid * 8; i < 16 * 256; i += 1024 * 8)
    *(i32x4*)&hbuf[0][i] = (i32x4){0, 0, 0, 0};
  float h[4];
  #pragma unroll
  for (int i = 0; i < 4; ++i) h[i] = 0.f;

  float gi[3][4];
  load_gi(bwd ? (SS - 1) : 0, gi);   // prologue: gi(0)
  __syncthreads();

  for (int step = 0; step < SS; ++step) {
    const u16* cur = hbuf[step & 1];
    u16* nxt = hbuf[(step & 1) ^ 1];
    int s = bwd ? (SS - 1 - step) : step;

    // ---- prefetch gi(t+1): issued before GEMM, waited after the barrier ----
    float gin[3][4];
    if (step + 1 < SS) {
      int sn = bwd ? (SS - 2 - step) : (step + 1);
      load_gi(sn, gin);
    }

    f32x4 acc[3];
    #pragma unroll
    for (int g = 0; g < 3; ++g) acc[g] = (f32x4){0.f, 0.f, 0.f, 0.f};
    #pragma unroll
    for (int k = 0; k < 8; ++k) {
      bf16x8 a = *(const bf16x8*)&cur[m * 256 + (((quad + 4 * k) ^ m) * 8)];
      #pragma unroll
      for (int g = 0; g < 3; ++g) {
        bf16x8 bv = *(const bf16x8*)(bp[g] + k * 32);
        acc[g] = __builtin_amdgcn_mfma_f32_16x16x32_bf16(a, bv, acc[g], 0, 0, 0);
      }
    }
    // no barrier: update writes the OTHER buffer
    int cc = c >> 3, lo = c & 7;
    #pragma unroll
    for (int i = 0; i < 4; ++i) {
      int row_l = quad * 4 + i;
      float rr = fsig(gi[0][i] + acc[0][i]);
      float zz = fsig(gi[1][i] + acc[1][i]);
      float nn = ftanh(gi[2][i] + rr * (acc[2][i] + nbv));
      float hv = (1.f - zz) * nn + zz * h[i];
      h[i] = hv;
      nxt[row_l * 256 + ((cc ^ row_l) * 8) + lo] = f2bf(hv);
      if (!isX2) {
        int bb = ((rt & 1) << 4) + row_l;
        size_t o = (size_t)(bb * SS + s) * 512 + (bwd ? 256 : 0) + c;
        sc[o] = hv;
        scbf[o] = f2bf(hv);
      }
    }
    __syncthreads();   // writes visible before next step's GEMM reads

    if (step + 1 < SS) {
      #pragma unroll
      for (int g = 0; g < 3; ++g)
        #pragma unroll
        for (int i = 0; i < 4; ++i) gi[g][i] = gin[g][i];
    }
  }
  if (isX2) {   // r = concat(r1f, r1b): finals of x2 fwd/bwd
    #pragma unroll
    for (int i = 0; i < 4; ++i) {
      int bb = ((rt & 1) << 4) + quad * 4 + i;
      size_t o = (size_t)bb * 512 + (bwd ? 256 : 0) + c;
      rvec[o] = h[i];
      rbf[o] = f2bf(h[i]);
    }
  }
}

__global__ void energies_k(const float* __restrict__ a, const float* __restrict__ r,
                           float* __restrict__ e) {
  int gid = blockIdx.x * blockDim.x + threadIdx.x;
  int wid = gid >> 6, lane = gid & 63;
  if (wid >= NSEQ) return;
  int b = wid / SS;
  const float* ar = a + (size_t)wid * 512;
  const float* rr = r + (size_t)b * 512;
  float sum = 0.f;
  for (int i = lane; i < 512; i += 64) sum += ar[i] * rr[i];
  for (int off = 32; off > 0; off >>= 1) sum += __shfl_down(sum, off);
  if (lane == 0) e[wid] = sum;
}

__global__ void softmax_k(const float* __restrict__ e, const float* __restrict__ mask,
                          float* __restrict__ alpha) {
  __shared__ float red[256];
  int b = blockIdx.x, tid = threadIdx.x;
  float v = (tid < SS) ? e[b * SS + tid] : -1e30f;
  red[tid] = v; __syncthreads();
  for (int s = 128; s > 0; s >>= 1) { if (tid < s) red[tid] = fmaxf(red[tid], red[tid + s]); __syncthreads(); }
  float mx = red[0]; __syncthreads();
  float ex = (tid < SS) ? expf(v - mx) : 0.f;
  red[tid] = ex; __syncthreads();
  for (int s = 128; s > 0; s >>= 1) { if (tid < s) red[tid] += red[tid + s]; __syncthreads(); }
  float denom = red[0];
  if (tid < SS) alpha[b * SS + tid] = ex / denom * mask[b * SS + tid];
}

__global__ void cattn_k(const float* __restrict__ alpha, const float* __restrict__ sc,
                        float* __restrict__ c) {
  int b = blockIdx.x, d = threadIdx.x;
  float sum = 0.f;
  for (int s = 0; s < SS; ++s)
    sum += alpha[b * SS + s] * sc[(size_t)(b * SS + s) * 512 + d];
  c[b * 512 + d] = sum;
}

__global__ void final_dot(const float* __restrict__ c, const float* __restrict__ v,
                          const float* __restrict__ bsc, float* __restrict__ out) {
  int b = blockIdx.x, lane = threadIdx.x;
  float s = 0.f;
  for (int i = lane; i < 512; i += 64) s += c[b * 512 + i] * v[b * 512 + i];
  for (int off = 32; off > 0; off >>= 1) s += __shfl_down(s, off);
  if (lane == 0) out[b] = s + bsc[0];
}

extern "C" void kernel_launch(void* const* d_in, const int* in_sizes, int n_in,
                              void* d_out, int out_size, void* d_ws, size_t ws_size,
                              hipStream_t stream) {
  const int*   x1     = (const int*)d_in[0];
  const int*   x2     = (const int*)d_in[1];
  const int*   keys_c = (const int*)d_in[2];
  const int*   keys_r = (const int*)d_in[3];
  const float* x1mask = (const float*)d_in[4];
  const float* emb    = (const float*)d_in[5];
  const float* kWif   = (const float*)d_in[6];
  const float* kWhf   = (const float*)d_in[7];
  const float* kbif   = (const float*)d_in[8];
  const float* kbhf   = (const float*)d_in[9];
  const float* kWib   = (const float*)d_in[10];
  const float* kWhb   = (const float*)d_in[11];
  const float* kbib   = (const float*)d_in[12];
  const float* kbhb   = (const float*)d_in[13];
  const float* eWif   = (const float*)d_in[14];
  const float* eWhf   = (const float*)d_in[15];
  const float* ebif   = (const float*)d_in[16];
  const float* ebhf   = (const float*)d_in[17];
  const float* eWib   = (const float*)d_in[18];
  const float* eWhb   = (const float*)d_in[19];
  const float* ebib   = (const float*)d_in[20];
  const float* ebhb   = (const float*)d_in[21];
  const float* attnW  = (const float*)d_in[22];
  const float* attnb  = (const float*)d_in[23];
  const float* Mw     = (const float*)d_in[24];
  const float* bsc    = (const float*)d_in[25];
  float* out = (float*)d_out;

  char* base = (char*)d_ws;
  size_t off = 0;
  auto take = [&](size_t bytes) -> void* {
    void* p = base + off; off += (bytes + 255) & ~(size_t)255; return p;
  };

  u16* kWif_bf = (u16*)take((size_t)G3 * EP * 2);
  u16* kWib_bf = (u16*)take((size_t)G3 * EP * 2);
  u8*  kW8f    = (u8*)take((size_t)G3 * HH);      // fp8 Whh fwd
  u8*  kW8b    = (u8*)take((size_t)G3 * HH);      // fp8 Whh bwd
  u16* eWif_bf = (u16*)take((size_t)G3 * EHP * 2);
  u16* eWib_bf = (u16*)take((size_t)G3 * EHP * 2);
  u16* eWhf_bf = (u16*)take((size_t)G3 * HH * 2);
  u16* eWhb_bf = (u16*)take((size_t)G3 * HH * 2);
  u16* attnW_bf = (u16*)take((size_t)512 * 512 * 2);
  u16* M_bf    = (u16*)take((size_t)512 * 512 * 2);
  u16* xe_bf   = (u16*)take((size_t)NROW * EHP * 2);
  float* cb_kf = (float*)take(G3 * 4);
  float* cb_kb = (float*)take(G3 * 4);
  float* cb_ef = (float*)take(G3 * 4);
  float* cb_eb = (float*)take(G3 * 4);
  float* h_key = (float*)take((size_t)NKEY * HH * 4);   // persistent: outlives overlay

  size_t pbase = off;
  u16* emb_bf = (u16*)take((size_t)VV * EP * 2);
  u8*  T8F    = (u8*)take((size_t)VV * 1024);   // packed key-table fwd
  u8*  T8B    = (u8*)take((size_t)VV * 1024);   // packed key-table bwd

  off = pbase;
  float* Gf = (float*)take((size_t)NROW * G3 * 4);
  float* Gb = (float*)take((size_t)NROW * G3 * 4);
  float* sc = (float*)take((size_t)NSEQ * 512 * 4);
  u16*   sc_bf = (u16*)take((size_t)NSEQ * 512 * 2);
  float* rvec = (float*)take((size_t)BB * 512 * 4);
  u16*   r_bf = (u16*)take((size_t)BB * 512 * 2);
  float* abuf = (float*)take((size_t)NSEQ * 512 * 4);
  float* energ = (float*)take((size_t)BB * SS * 4);
  float* alpha = (float*)take((size_t)BB * SS * 4);
  float* c_attn = (float*)take((size_t)BB * 512 * 4);
  float* vbuf = (float*)take((size_t)BB * 512 * 4);

  auto cvt = [&](const float* s, u16* d, int rows, int K, int ldp) {
    int tot = rows * ldp;
    cvt_pad<<<(tot + 255) / 256, 256, 0, stream>>>(s, d, rows, K, ldp);
  };
  auto gemm = [&](const u16* A, const u16* B, float* C, u16* Cbf, u8* C8,
                  const float* bias,
                  int M, int N, int K, int lda, int ldb, int ldc) {
    long long waves = (long long)(M >> 5) * (N >> 6);
    int blocks = (int)((waves * 64 + 255) / 256);
    gemm_bt24<<<blocks, 256, 0, stream>>>(A, B, C, Cbf, C8, bias, M, N, K, lda, ldb, ldc);
  };

  cvt(emb, emb_bf, VV, EE, EP);
  cvt(kWif, kWif_bf, G3, EE, EP);
  cvt(kWib, kWib_bf, G3, EE, EP);
  cvt_f8<<<(G3 * HH + 255) / 256, 256, 0, stream>>>(kWhf, kW8f, G3 * HH);
  cvt_f8<<<(G3 * HH + 255) / 256, 256, 0, stream>>>(kWhb, kW8b, G3 * HH);
  cvt(eWif, eWif_bf, G3, 556, EHP);
  cvt(eWib, eWib_bf, G3, 556, EHP);
  cvt(eWhf, eWhf_bf, G3, HH, HH);
  cvt(eWhb, eWhb_bf, G3, HH, HH);
  cvt(attnW, attnW_bf, 512, 512, 512);
  cvt(Mw, M_bf, 512, 512, 512);
  bias_comb<<<3, 256, 0, stream>>>(kbif, kbhf, cb_kf);
  bias_comb<<<3, 256, 0, stream>>>(kbib, kbhb, cb_kb);
  bias_comb<<<3, 256, 0, stream>>>(ebif, ebhf, cb_ef);
  bias_comb<<<3, 256, 0, stream>>>(ebib, ebhb, cb_eb);

  gemm(emb_bf, kWif_bf, nullptr, nullptr, T8F, cb_kf, VV, G3, EP, EP, EP, G3);
  gemm(emb_bf, kWib_bf, nullptr, nullptr, T8B, cb_kb, VV, G3, EP, EP, EP, G3);

  key_gru16<<<256, 1024, 0, stream>>>(kW8f, kW8b, kbhf, kbhb,
                                      T8F, T8B, keys_c, keys_r, h_key);

  build_xe<<<(NROW * EHP + 255) / 256, 256, 0, stream>>>(emb, x1, x2, h_key, xe_bf);

  gemm(xe_bf, eWif_bf, Gf, nullptr, nullptr, cb_ef, NROW, G3, EHP, EHP, EHP, G3);
  gemm(xe_bf, eWib_bf, Gb, nullptr, nullptr, cb_eb, NROW, G3, EHP, EHP, EHP, G3);

  main_gru5<<<8, 1024, 0, stream>>>(eWhf_bf, eWhb_bf, ebhf, ebhb,
                                    Gf, Gb, sc, sc_bf, rvec, r_bf);

  gemm(sc_bf, attnW_bf, abuf, nullptr, nullptr, attnb, NSEQ, 512, 512, 512, 512, 512);
  energies_k<<<(NSEQ * 64 + 255) / 256, 256, 0, stream>>>(abuf, rvec, energ);
  softmax_k<<<BB, 256, 0, stream>>>(energ, x1mask, alpha);
  cattn_k<<<BB, 512, 0, stream>>>(alpha, sc, c_attn);
  gemm(r_bf, M_bf, vbuf, nullptr, nullptr, nullptr, BB, 512, 512, 512, 512, 512);
  final_dot<<<BB, 64, 0, stream>>>(c_attn, vbuf, bsc, out);
}

// Round 11
// 1958.473 us; speedup vs baseline: 1.1151x; 1.1151x over previous
//
#include <hip/hip_runtime.h>
#include <hip/hip_bf16.h>

#define BB 32
#define SS 160
#define KK 44
#define EE 300
#define HH 256
#define VV 32000
#define G3 768
#define EHP 576
#define EP  320
#define NSEQ 5120
#define NROW 10240
#define NKEY 20480

typedef unsigned short u16;
typedef unsigned char u8;
typedef long i64;
typedef __attribute__((ext_vector_type(8))) short bf16x8;
typedef __attribute__((ext_vector_type(4))) float f32x4;
typedef __attribute__((ext_vector_type(2))) float f32x2;
typedef __attribute__((ext_vector_type(4))) int i32x4;

static __device__ __forceinline__ u16 f2bf(float f) {
  union { float f; unsigned u; } x; x.f = f;
  unsigned u = x.u;
  unsigned r = (u + 0x7fffu + ((u >> 16) & 1u)) >> 16;
  return (u16)r;
}
static __device__ __forceinline__ float bf2f(u16 v) {
  union { unsigned u; float f; } x; x.u = ((unsigned)v) << 16;
  return x.f;
}
static __device__ __forceinline__ u8 ftofp8(float v) {
  return (u8)(__builtin_amdgcn_cvt_pk_fp8_f32(v, v, 0, false) & 0xff);
}
static __device__ __forceinline__ float fsig(float x) {
  float e = __expf(-x);
  return __builtin_amdgcn_rcpf(1.f + e);
}
static __device__ __forceinline__ float ftanh(float x) {
  float e = __expf(2.f * x);
  return 1.f - 2.f * __builtin_amdgcn_rcpf(1.f + e);
}

// fp32 (rows,K) -> bf16 (rows,ldp), zero pad cols K..ldp
__global__ void cvt_pad(const float* __restrict__ src, u16* __restrict__ dst,
                        int rows, int K, int ldp) {
  int idx = blockIdx.x * blockDim.x + threadIdx.x;
  int tot = rows * ldp;
  if (idx >= tot) return;
  int c = idx % ldp; int r = idx / ldp;
  float v = (c < K) ? src[(size_t)r * K + c] : 0.f;
  dst[idx] = f2bf(v);
}

// fp32 -> fp8 e4m3, flat
__global__ void cvt_f8(const float* __restrict__ src, u8* __restrict__ dst, int n) {
  int i = blockIdx.x * blockDim.x + threadIdx.x;
  if (i < n) dst[i] = ftofp8(src[i]);
}

// o[j] = bi[j] + (j<512 ? bh[j] : 0)
__global__ void bias_comb(const float* __restrict__ bi, const float* __restrict__ bh,
                          float* __restrict__ o) {
  int j = blockIdx.x * blockDim.x + threadIdx.x;
  if (j >= G3) return;
  o[j] = bi[j] + (j < 512 ? bh[j] : 0.f);
}

// C = A @ B^T + bias; 2 row-tiles x 4 col-tiles per wave.
// Output modes: C fp32 | Cbf bf16 | C8 = packed key-table rows:
//   row = 1024B: bytes[2c]=r-fp8, bytes[2c+1]=z-fp8, bytes[512+2c..]=n-bf16.
__global__ void gemm_bt24(const u16* __restrict__ A, const u16* __restrict__ B,
                          float* __restrict__ C, u16* __restrict__ Cbf,
                          u8* __restrict__ C8,
                          const float* __restrict__ bias,
                          int M, int N, int K, int lda, int ldb, int ldc) {
  int gid = blockIdx.x * blockDim.x + threadIdx.x;
  int wid = gid >> 6, lane = gid & 63;
  int ntg = N >> 6;
  int total = (M >> 5) * ntg;
  if (wid >= total) return;
  int tm = wid / ntg, tg = wid - tm * ntg;
  int rbase = tm << 5, cbase = tg << 6;
  int m = lane & 15, quad = lane >> 4;
  const u16* ap0 = A + (size_t)(rbase + m) * lda + quad * 8;
  const u16* ap1 = ap0 + (size_t)16 * lda;
  const u16* bp0 = B + (size_t)(cbase + m) * ldb + quad * 8;
  f32x4 acc[2][4];
  #pragma unroll
  for (int r = 0; r < 2; ++r)
    #pragma unroll
    for (int c = 0; c < 4; ++c) acc[r][c] = (f32x4){0.f, 0.f, 0.f, 0.f};
  for (int k = 0; k < K; k += 32) {
    bf16x8 a0 = *(const bf16x8*)(ap0 + k);
    bf16x8 a1 = *(const bf16x8*)(ap1 + k);
    #pragma unroll
    for (int c = 0; c < 4; ++c) {
      bf16x8 bv = *(const bf16x8*)(bp0 + (size_t)c * 16 * ldb + k);
      acc[0][c] = __builtin_amdgcn_mfma_f32_16x16x32_bf16(a0, bv, acc[0][c], 0, 0, 0);
      acc[1][c] = __builtin_amdgcn_mfma_f32_16x16x32_bf16(a1, bv, acc[1][c], 0, 0, 0);
    }
  }
  #pragma unroll
  for (int c = 0; c < 4; ++c) {
    int col = cbase + c * 16 + m;
    float bv = bias ? bias[col] : 0.f;
    int g = col >> 8, cc = col & 255;   // gate / in-gate col (C8 mode)
    #pragma unroll
    for (int rt = 0; rt < 2; ++rt) {
      int orow = rbase + rt * 16 + quad * 4;
      #pragma unroll
      for (int i = 0; i < 4; ++i) {
        float v = acc[rt][c][i] + bv;
        if (C8) {
          size_t rb = (size_t)(orow + i) * 1024;
          if (g < 2) C8[rb + 2 * cc + g] = ftofp8(v);
          else *(u16*)&C8[rb + 512 + 2 * cc] = f2bf(v);
        } else if (Cbf) Cbf[(size_t)(orow + i) * ldc + col] = f2bf(v);
        else C[(size_t)(orow + i) * ldc + col] = v;
      }
    }
  }
}

// Async global->LDS 16B gather; aux=0 (policy bits proved irrelevant r8/r10)
#define GLD16(gsrc, ldst)                                                     \
  __builtin_amdgcn_global_load_lds(                                           \
      (const __attribute__((address_space(1))) void*)(gsrc),                  \
      (__attribute__((address_space(3))) void*)(ldst), 16, 0, 0)

// ---- Persistent key-GRU v16 (unchanged R9 winner): W-in-regs, depth-5
// counted-vmcnt gather, 6-slot rotating giL, 6 barriers + 1 drain/step. ----
__global__ __launch_bounds__(1024) void key_gru16(
    const u8* __restrict__ W8f, const u8* __restrict__ W8b,
    const float* __restrict__ nbf, const float* __restrict__ nbb,
    const u8* __restrict__ T8F, const u8* __restrict__ T8B,
    const int* __restrict__ keys_c, const int* __restrict__ keys_r,
    float* __restrict__ h_out) {
  __shared__ __align__(16) u8 hb8[2][80 * 256];  // 2x20 KB ping-pong fp8 h
  __shared__ __align__(16) u8 giL[6 * 16384];    // 96 KB, 6 rotating slots
  __shared__ int tokL[80 * KK];                  // 14 KB token slice
  int b = blockIdx.x;
  int xcd = b & 7, slot0 = b >> 3;
  int bwd = xcd >> 2;
  int j = slot0 * 4 + (xcd & 3);
  int isR = j >> 6;
  int seq0 = (j & 63) * 80;
  const u8* W8 = bwd ? W8b : W8f;
  const u8* T = bwd ? T8B : T8F;
  const int* keys = isR ? keys_r : keys_c;
  const float* nb = bwd ? nbb : nbf;

  int tid = threadIdx.x;
  int w = tid >> 6, lane = tid & 63, m = lane & 15, quad = lane >> 4;
  int c = w * 16 + m;               // this thread's output column (0..255)
  float nbv = nb[512 + c];

  // Token slice: contiguous copy keys[seq0*KK .. (seq0+80)*KK) -> LDS.
  for (int i = tid; i < 80 * KK; i += 1024)
    tokL[i] = keys[seq0 * KK + i];

  // Whh in registers: same 192B per thread for the whole kernel.
  i64 w_r[8], w_z[8], w_n[8];
  {
    const u8* br = W8 + (size_t)(0 * 256 + c) * 256 + quad * 8;
    const u8* bz = W8 + (size_t)(1 * 256 + c) * 256 + quad * 8;
    const u8* bn = W8 + (size_t)(2 * 256 + c) * 256 + quad * 8;
    #pragma unroll
    for (int kc = 0; kc < 8; ++kc) {
      w_r[kc] = *(const i64*)(br + kc * 32);
      w_z[kc] = *(const i64*)(bz + kc * 32);
      w_n[kc] = *(const i64*)(bn + kc * 32);
    }
  }

  // Group g rows [g*16, g*16+16): one 1-row-per-wave GLD16 into slot `sl`.
  auto dma_grp = [&](int tt, int g, int sl) {
    int row = g * 16 + w;
    int tok = tokL[row * KK + tt];                   // wave-uniform ds_read
    const u8* src = T + (size_t)tok * 1024 + lane * 16;
    u8* dst = giL + sl * 16384 + w * 1024;           // + lane*16B by HW
    GLD16(src, dst);
  };

  for (int i = tid * 16; i < 80 * 256; i += 1024 * 16)
    *(i32x4*)&hb8[0][i] = (i32x4){0, 0, 0, 0};
  float h[5][4];
  #pragma unroll
  for (int rt = 0; rt < 5; ++rt)
    #pragma unroll
    for (int i = 0; i < 4; ++i) h[rt][i] = 0.f;

  // Drain ALL prologue vmem so the in-loop per-thread vmcnt stream is exactly
  // the 5 GLD16s/step; tokL + hb8 zeros visible before any dma_grp reads.
  asm volatile("s_waitcnt vmcnt(0) lgkmcnt(0)" ::: "memory");
  __builtin_amdgcn_s_barrier();

  {
    int t0 = bwd ? (KK - 1) : 0;
    #pragma unroll
    for (int g = 0; g < 5; ++g) dma_grp(t0, g, g);   // FIFO: grp0..grp4
  }

  int cc = c >> 3, lo = c & 7;
  int sb = 0;   // slot base: slot(t,g) = (g + sb) % 6; sb(t) = (-t) mod 6

  for (int step = 0; step < KK; ++step) {
    const u8* cur = hb8[step & 1];
    u8* nxt = hb8[(step & 1) ^ 1];
    int tnext = bwd ? (KK - 2 - step) : (step + 1);
    int tclamp = tnext < 0 ? 0 : (tnext > KK - 1 ? KK - 1 : tnext);  // dummy on last step

    #pragma unroll
    for (int rt = 0; rt < 5; ++rt) {
      // ---- GEMM(rt): reads only hb8 rows rt*16..rt*16+15 of cur ----
      f32x4 acc[3];
      #pragma unroll
      for (int g = 0; g < 3; ++g) acc[g] = (f32x4){0.f, 0.f, 0.f, 0.f};
      int arow = rt * 16 + m;
      #pragma unroll
      for (int kc = 0; kc < 8; ++kc) {
        i64 a = *(const i64*)&cur[arow * 256 + (((quad + 4 * kc) ^ (arow & 31)) * 8)];
        acc[0] = __builtin_amdgcn_mfma_f32_16x16x32_fp8_fp8(a, w_r[kc], acc[0], 0, 0, 0);
        acc[1] = __builtin_amdgcn_mfma_f32_16x16x32_fp8_fp8(a, w_z[kc], acc[1], 0, 0, 0);
        acc[2] = __builtin_amdgcn_mfma_f32_16x16x32_fp8_fp8(a, w_n[kc], acc[2], 0, 0, 0);
      }

      // ---- retire exactly group rt(t); keep 4 gathers in flight.
      // Also certifies all waves completed update(rt-1) -> its slot is free.
      asm volatile("s_waitcnt vmcnt(4)" ::: "memory");
      __builtin_amdgcn_s_barrier();
      __builtin_amdgcn_sched_barrier(0);

      // ---- update(rt): reads giL slot(t,rt), writes nxt rows rt ----
      const u16* giU = (const u16*)(giL + ((rt + sb) % 6) * 16384);
      #pragma unroll
      for (int i = 0; i < 4; ++i) {
        int lrow = quad * 4 + i;
        int row = rt * 16 + lrow;
        u16 vrz = giU[lrow * 512 + c];
        f32x2 grz = __builtin_amdgcn_cvt_pk_f32_fp8((int)vrz, false);
        float gn = bf2f(giU[lrow * 512 + 256 + c]);
        float rr = fsig(grz[0] + acc[0][i]);
        float zz = fsig(grz[1] + acc[1][i]);
        float nn = ftanh(gn + rr * (acc[2][i] + nbv));
        float hv = (1.f - zz) * nn + zz * h[rt][i];
        h[rt][i] = hv;
        nxt[row * 256 + ((cc ^ (row & 31)) * 8) + lo] = ftofp8(hv);
      }
      __builtin_amdgcn_sched_barrier(0);  // cap live range per rt-group
      // dma group rt(t+1) into slot(t+1,rt) = slot(t,rt-1) (rt=0 -> free slot)
      dma_grp(tclamp, rt, (rt + sb + 5) % 6);
    }

    // ---- step end: hb8[nxt] writes visible to all waves' next GEMM ----
    asm volatile("s_waitcnt lgkmcnt(0)" ::: "memory");
    __builtin_amdgcn_s_barrier();
    sb = (sb + 5) % 6;
  }

  // Coalesced fp32 epilogue via giL staging (drains dummy DMAs first)
  __syncthreads();
  float* hstage = (float*)giL;
  #pragma unroll
  for (int rt = 0; rt < 5; ++rt)
    #pragma unroll
    for (int i = 0; i < 4; ++i)
      hstage[(rt * 16 + quad * 4 + i) * 256 + c] = h[rt][i];
  __syncthreads();
  size_t rowbase = (size_t)(bwd * NROW + isR * NSEQ + seq0) * 256;
  for (int i = tid * 4; i < 80 * 256; i += 1024 * 4)
    *(f32x4*)&h_out[rowbase + i] = *(const f32x4*)&hstage[i];
}

// Build concat inputs for the main GRU, bf16 padded.
__global__ void build_xe(const float* __restrict__ emb, const int* __restrict__ x1,
                         const int* __restrict__ x2, const float* __restrict__ hk,
                         u16* __restrict__ xe) {
  int idx = blockIdx.x * blockDim.x + threadIdx.x;
  if (idx >= NROW * EHP) return;
  int c = idx % EHP; int rr = idx / EHP;
  int isX2 = rr >= NSEQ;
  int seq = rr - (isX2 ? NSEQ : 0);
  float v;
  if (c < EE) {
    int tok = (isX2 ? x2 : x1)[seq];
    v = emb[(size_t)tok * EE + c];
  } else if (c < EE + HH) {
    int j = c - EE;
    int frow = (isX2 ? NSEQ : 0) + seq;
    v = hk[(size_t)frow * HH + j] + hk[(size_t)(NROW + frow) * HH + j];
  } else {
    v = 0.f;
  }
  xe[idx] = f2bf(v);
}

// ---- Persistent main GRU v6: LDS double-buffered gi via global_load_lds +
// counted vmcnt + RAW barriers (the key_gru16 pattern).
// R10 lesson: register prefetch across __syncthreads is futile -- hipcc
// emits s_waitcnt vmcnt(0) lgkmcnt(0) before s_barrier, and holding loads
// live across the barrier made it wait EARLY (735->1003us). v6: gi(t) =
// 16 G-rows x 3072B = 48KB staged in LDS (2 bufs); wave w DMAs row w of
// step t+1 (3 GLD16) at step top. s_waitcnt vmcnt(3) is safe for ANY
// compiler store count: the 3 newest VMEM ops are exactly the t+1 DMAs,
// so all older (DMA(t), stores(t-1)) are retired; raw s_barrier then makes
// giL(t) visible to all waves WITHOUT draining DMA(t+1) -> full-step cover.
// Second raw barrier after lgkmcnt(0): hbuf[nxt] visible + giB(t) reads
// done before t+2's DMA overwrites. Math identical to v4.
__global__ __launch_bounds__(1024, 1) void main_gru6(
    const u16* __restrict__ Wf, const u16* __restrict__ Wb,
    const float* __restrict__ nbf, const float* __restrict__ nbb,
    const float* __restrict__ Gf, const float* __restrict__ Gb,
    float* __restrict__ sc, u16* __restrict__ scbf,
    float* __restrict__ rvec, u16* __restrict__ rbf) {
  __shared__ __align__(16) u16 hbuf[2][16 * 256];   // 16 KB
  __shared__ __align__(16) u8 giB[2][16 * 3072];    // 96 KB gi double-buffer
  int rt = blockIdx.x;
  int q = rt >> 1;
  int bwd = q >> 1, isX2 = q & 1;
  const u16* W = bwd ? Wb : Wf;
  const float* G = bwd ? Gb : Gf;
  const float* nb = bwd ? nbb : nbf;
  int tid = threadIdx.x, w = tid >> 6, lane = tid & 63, m = lane & 15, quad = lane >> 4;
  int c = w * 16 + m;
  float nbv = nb[512 + c];

  const u16* bp[3];
  #pragma unroll
  for (int g = 0; g < 3; ++g)
    bp[g] = W + (size_t)(g * 256 + c) * 256 + quad * 8;

  // Wave w DMAs G-row bb=(rt&1)*16+w of timestep s: 3072B = 3 x GLD16.
  auto dma_gi = [&](int s, int buf) {
    size_t rowbase = ((size_t)(isX2 * NSEQ + (((rt & 1) << 4) + w) * SS + s)) * G3;
    const u8* src = (const u8*)(G + rowbase) + lane * 16;
    u8* dst = giB[buf] + w * 3072;                  // + lane*16B by HW
    #pragma unroll
    for (int ch = 0; ch < 3; ++ch)
      GLD16(src + ch * 1024, dst + ch * 1024);
  };

  for (int i = tid * 8; i < 16 * 256; i += 1024 * 8)
    *(i32x4*)&hbuf[0][i] = (i32x4){0, 0, 0, 0};
  float h[4];
  #pragma unroll
  for (int i = 0; i < 4; ++i) h[i] = 0.f;

  dma_gi(bwd ? (SS - 1) : 0, 0);
  asm volatile("s_waitcnt vmcnt(0) lgkmcnt(0)" ::: "memory");
  __builtin_amdgcn_s_barrier();   // gi(0) landed + hbuf zeros visible

  for (int step = 0; step < SS; ++step) {
    const u16* cur = hbuf[step & 1];
    u16* nxt = hbuf[(step & 1) ^ 1];
    int s = bwd ? (SS - 1 - step) : step;
    int sn = bwd ? (SS - 2 - step) : (step + 1);
    int snc = sn < 0 ? 0 : (sn > SS - 1 ? SS - 1 : sn);   // dummy on last step

    // ---- issue DMA gi(t+1) into the other buffer; flies across barriers ----
    dma_gi(snc, (step & 1) ^ 1);

    f32x4 acc[3];
    #pragma unroll
    for (int g = 0; g < 3; ++g) acc[g] = (f32x4){0.f, 0.f, 0.f, 0.f};
    #pragma unroll
    for (int k = 0; k < 8; ++k) {
      bf16x8 a = *(const bf16x8*)&cur[m * 256 + (((quad + 4 * k) ^ m) * 8)];
      #pragma unroll
      for (int g = 0; g < 3; ++g) {
        bf16x8 bv = *(const bf16x8*)(bp[g] + k * 32);
        acc[g] = __builtin_amdgcn_mfma_f32_16x16x32_bf16(a, bv, acc[g], 0, 0, 0);
      }
    }

    // ---- retire DMA(t) (3 newest in flight = DMA(t+1)); cross-wave gate ----
    asm volatile("s_waitcnt vmcnt(3)" ::: "memory");
    __builtin_amdgcn_s_barrier();
    __builtin_amdgcn_sched_barrier(0);

    // ---- update: gi from LDS; write nxt + sc/scbf ----
    const u8* giC = giB[step & 1];
    int cc = c >> 3, lo = c & 7;
    #pragma unroll
    for (int i = 0; i < 4; ++i) {
      int r = quad * 4 + i;
      const float* gr = (const float*)(giC + r * 3072);
      float g0 = gr[0 * 256 + c];
      float g1 = gr[1 * 256 + c];
      float g2 = gr[2 * 256 + c];
      float rr = fsig(g0 + acc[0][i]);
      float zz = fsig(g1 + acc[1][i]);
      float nn = ftanh(g2 + rr * (acc[2][i] + nbv));
      float hv = (1.f - zz) * nn + zz * h[i];
      h[i] = hv;
      nxt[r * 256 + ((cc ^ r) * 8) + lo] = f2bf(hv);
      if (!isX2) {
        int bb = ((rt & 1) << 4) + r;
        size_t o = (size_t)(bb * SS + s) * 512 + (bwd ? 256 : 0) + c;
        sc[o] = hv;
        scbf[o] = f2bf(hv);
      }
    }

    // ---- hbuf[nxt] visible + giB(t) reads done (before t+2 overwrite) ----
    asm volatile("s_waitcnt lgkmcnt(0)" ::: "memory");
    __builtin_amdgcn_s_barrier();
  }
  if (isX2) {   // r = concat(r1f, r1b): finals of x2 fwd/bwd
    #pragma unroll
    for (int i = 0; i < 4; ++i) {
      int bb = ((rt & 1) << 4) + quad * 4 + i;
      size_t o = (size_t)bb * 512 + (bwd ? 256 : 0) + c;
      rvec[o] = h[i];
      rbf[o] = f2bf(h[i]);
    }
  }
}

__global__ void energies_k(const float* __restrict__ a, const float* __restrict__ r,
                           float* __restrict__ e) {
  int gid = blockIdx.x * blockDim.x + threadIdx.x;
  int wid = gid >> 6, lane = gid & 63;
  if (wid >= NSEQ) return;
  int b = wid / SS;
  const float* ar = a + (size_t)wid * 512;
  const float* rr = r + (size_t)b * 512;
  float sum = 0.f;
  for (int i = lane; i < 512; i += 64) sum += ar[i] * rr[i];
  for (int off = 32; off > 0; off >>= 1) sum += __shfl_down(sum, off);
  if (lane == 0) e[wid] = sum;
}

__global__ void softmax_k(const float* __restrict__ e, const float* __restrict__ mask,
                          float* __restrict__ alpha) {
  __shared__ float red[256];
  int b = blockIdx.x, tid = threadIdx.x;
  float v = (tid < SS) ? e[b * SS + tid] : -1e30f;
  red[tid] = v; __syncthreads();
  for (int s = 128; s > 0; s >>= 1) { if (tid < s) red[tid] = fmaxf(red[tid], red[tid + s]); __syncthreads(); }
  float mx = red[0]; __syncthreads();
  float ex = (tid < SS) ? expf(v - mx) : 0.f;
  red[tid] = ex; __syncthreads();
  for (int s = 128; s > 0; s >>= 1) { if (tid < s) red[tid] += red[tid + s]; __syncthreads(); }
  float denom = red[0];
  if (tid < SS) alpha[b * SS + tid] = ex / denom * mask[b * SS + tid];
}

__global__ void cattn_k(const float* __restrict__ alpha, const float* __restrict__ sc,
                        float* __restrict__ c) {
  int b = blockIdx.x, d = threadIdx.x;
  float sum = 0.f;
  for (int s = 0; s < SS; ++s)
    sum += alpha[b * SS + s] * sc[(size_t)(b * SS + s) * 512 + d];
  c[b * 512 + d] = sum;
}

__global__ void final_dot(const float* __restrict__ c, const float* __restrict__ v,
                          const float* __restrict__ bsc, float* __restrict__ out) {
  int b = blockIdx.x, lane = threadIdx.x;
  float s = 0.f;
  for (int i = lane; i < 512; i += 64) s += c[b * 512 + i] * v[b * 512 + i];
  for (int off = 32; off > 0; off >>= 1) s += __shfl_down(s, off);
  if (lane == 0) out[b] = s + bsc[0];
}

extern "C" void kernel_launch(void* const* d_in, const int* in_sizes, int n_in,
                              void* d_out, int out_size, void* d_ws, size_t ws_size,
                              hipStream_t stream) {
  const int*   x1     = (const int*)d_in[0];
  const int*   x2     = (const int*)d_in[1];
  const int*   keys_c = (const int*)d_in[2];
  const int*   keys_r = (const int*)d_in[3];
  const float* x1mask = (const float*)d_in[4];
  const float* emb    = (const float*)d_in[5];
  const float* kWif   = (const float*)d_in[6];
  const float* kWhf   = (const float*)d_in[7];
  const float* kbif   = (const float*)d_in[8];
  const float* kbhf   = (const float*)d_in[9];
  const float* kWib   = (const float*)d_in[10];
  const float* kWhb   = (const float*)d_in[11];
  const float* kbib   = (const float*)d_in[12];
  const float* kbhb   = (const float*)d_in[13];
  const float* eWif   = (const float*)d_in[14];
  const float* eWhf   = (const float*)d_in[15];
  const float* ebif   = (const float*)d_in[16];
  const float* ebhf   = (const float*)d_in[17];
  const float* eWib   = (const float*)d_in[18];
  const float* eWhb   = (const float*)d_in[19];
  const float* ebib   = (const float*)d_in[20];
  const float* ebhb   = (const float*)d_in[21];
  const float* attnW  = (const float*)d_in[22];
  const float* attnb  = (const float*)d_in[23];
  const float* Mw     = (const float*)d_in[24];
  const float* bsc    = (const float*)d_in[25];
  float* out = (float*)d_out;

  char* base = (char*)d_ws;
  size_t off = 0;
  auto take = [&](size_t bytes) -> void* {
    void* p = base + off; off += (bytes + 255) & ~(size_t)255; return p;
  };

  u16* kWif_bf = (u16*)take((size_t)G3 * EP * 2);
  u16* kWib_bf = (u16*)take((size_t)G3 * EP * 2);
  u8*  kW8f    = (u8*)take((size_t)G3 * HH);      // fp8 Whh fwd
  u8*  kW8b    = (u8*)take((size_t)G3 * HH);      // fp8 Whh bwd
  u16* eWif_bf = (u16*)take((size_t)G3 * EHP * 2);
  u16* eWib_bf = (u16*)take((size_t)G3 * EHP * 2);
  u16* eWhf_bf = (u16*)take((size_t)G3 * HH * 2);
  u16* eWhb_bf = (u16*)take((size_t)G3 * HH * 2);
  u16* attnW_bf = (u16*)take((size_t)512 * 512 * 2);
  u16* M_bf    = (u16*)take((size_t)512 * 512 * 2);
  u16* xe_bf   = (u16*)take((size_t)NROW * EHP * 2);
  float* cb_kf = (float*)take(G3 * 4);
  float* cb_kb = (float*)take(G3 * 4);
  float* cb_ef = (float*)take(G3 * 4);
  float* cb_eb = (float*)take(G3 * 4);
  float* h_key = (float*)take((size_t)NKEY * HH * 4);   // persistent: outlives overlay

  size_t pbase = off;
  u16* emb_bf = (u16*)take((size_t)VV * EP * 2);
  u8*  T8F    = (u8*)take((size_t)VV * 1024);   // packed key-table fwd
  u8*  T8B    = (u8*)take((size_t)VV * 1024);   // packed key-table bwd

  off = pbase;
  float* Gf = (float*)take((size_t)NROW * G3 * 4);
  float* Gb = (float*)take((size_t)NROW * G3 * 4);
  float* sc = (float*)take((size_t)NSEQ * 512 * 4);
  u16*   sc_bf = (u16*)take((size_t)NSEQ * 512 * 2);
  float* rvec = (float*)take((size_t)BB * 512 * 4);
  u16*   r_bf = (u16*)take((size_t)BB * 512 * 2);
  float* abuf = (float*)take((size_t)NSEQ * 512 * 4);
  float* energ = (float*)take((size_t)BB * SS * 4);
  float* alpha = (float*)take((size_t)BB * SS * 4);
  float* c_attn = (float*)take((size_t)BB * 512 * 4);
  float* vbuf = (float*)take((size_t)BB * 512 * 4);

  auto cvt = [&](const float* s, u16* d, int rows, int K, int ldp) {
    int tot = rows * ldp;
    cvt_pad<<<(tot + 255) / 256, 256, 0, stream>>>(s, d, rows, K, ldp);
  };
  auto gemm = [&](const u16* A, const u16* B, float* C, u16* Cbf, u8* C8,
                  const float* bias,
                  int M, int N, int K, int lda, int ldb, int ldc) {
    long long waves = (long long)(M >> 5) * (N >> 6);
    int blocks = (int)((waves * 64 + 255) / 256);
    gemm_bt24<<<blocks, 256, 0, stream>>>(A, B, C, Cbf, C8, bias, M, N, K, lda, ldb, ldc);
  };

  cvt(emb, emb_bf, VV, EE, EP);
  cvt(kWif, kWif_bf, G3, EE, EP);
  cvt(kWib, kWib_bf, G3, EE, EP);
  cvt_f8<<<(G3 * HH + 255) / 256, 256, 0, stream>>>(kWhf, kW8f, G3 * HH);
  cvt_f8<<<(G3 * HH + 255) / 256, 256, 0, stream>>>(kWhb, kW8b, G3 * HH);
  cvt(eWif, eWif_bf, G3, 556, EHP);
  cvt(eWib, eWib_bf, G3, 556, EHP);
  cvt(eWhf, eWhf_bf, G3, HH, HH);
  cvt(eWhb, eWhb_bf, G3, HH, HH);
  cvt(attnW, attnW_bf, 512, 512, 512);
  cvt(Mw, M_bf, 512, 512, 512);
  bias_comb<<<3, 256, 0, stream>>>(kbif, kbhf, cb_kf);
  bias_comb<<<3, 256, 0, stream>>>(kbib, kbhb, cb_kb);
  bias_comb<<<3, 256, 0, stream>>>(ebif, ebhf, cb_ef);
  bias_comb<<<3, 256, 0, stream>>>(ebib, ebhb, cb_eb);

  gemm(emb_bf, kWif_bf, nullptr, nullptr, T8F, cb_kf, VV, G3, EP, EP, EP, G3);
  gemm(emb_bf, kWib_bf, nullptr, nullptr, T8B, cb_kb, VV, G3, EP, EP, EP, G3);

  key_gru16<<<256, 1024, 0, stream>>>(kW8f, kW8b, kbhf, kbhb,
                                      T8F, T8B, keys_c, keys_r, h_key);

  build_xe<<<(NROW * EHP + 255) / 256, 256, 0, stream>>>(emb, x1, x2, h_key, xe_bf);

  gemm(xe_bf, eWif_bf, Gf, nullptr, nullptr, cb_ef, NROW, G3, EHP, EHP, EHP, G3);
  gemm(xe_bf, eWib_bf, Gb, nullptr, nullptr, cb_eb, NROW, G3, EHP, EHP, EHP, G3);

  main_gru6<<<8, 1024, 0, stream>>>(eWhf_bf, eWhb_bf, ebhf, ebhb,
                                    Gf, Gb, sc, sc_bf, rvec, r_bf);

  gemm(sc_bf, attnW_bf, abuf, nullptr, nullptr, attnb, NSEQ, 512, 512, 512, 512, 512);
  energies_k<<<(NSEQ * 64 + 255) / 256, 256, 0, stream>>>(abuf, rvec, energ);
  softmax_k<<<BB, 256, 0, stream>>>(energ, x1mask, alpha);
  cattn_k<<<BB, 512, 0, stream>>>(alpha, sc, c_attn);
  gemm(r_bf, M_bf, vbuf, nullptr, nullptr, nullptr, BB, 512, 512, 512, 512, 512);
  final_dot<<<BB, 64, 0, stream>>>(c_attn, vbuf, bsc, out);
}

// Round 12
// 1762.323 us; speedup vs baseline: 1.2392x; 1.1113x over previous
//
#include <hip/hip_runtime.h>
#include <hip/hip_bf16.h>

#define BB 32
#define SS 160
#define KK 44
#define EE 300
#define HH 256
#define VV 32000
#define G3 768
#define EHP 576
#define EP  320
#define NSEQ 5120
#define NROW 10240
#define NKEY 20480

typedef unsigned short u16;
typedef unsigned char u8;
typedef long i64;
typedef __attribute__((ext_vector_type(8))) short bf16x8;
typedef __attribute__((ext_vector_type(4))) float f32x4;
typedef __attribute__((ext_vector_type(2))) float f32x2;
typedef __attribute__((ext_vector_type(4))) int i32x4;

static __device__ __forceinline__ u16 f2bf(float f) {
  union { float f; unsigned u; } x; x.f = f;
  unsigned u = x.u;
  unsigned r = (u + 0x7fffu + ((u >> 16) & 1u)) >> 16;
  return (u16)r;
}
static __device__ __forceinline__ float bf2f(u16 v) {
  union { unsigned u; float f; } x; x.u = ((unsigned)v) << 16;
  return x.f;
}
static __device__ __forceinline__ u8 ftofp8(float v) {
  return (u8)(__builtin_amdgcn_cvt_pk_fp8_f32(v, v, 0, false) & 0xff);
}
static __device__ __forceinline__ float fsig(float x) {
  float e = __expf(-x);
  return __builtin_amdgcn_rcpf(1.f + e);
}
static __device__ __forceinline__ float ftanh(float x) {
  float e = __expf(2.f * x);
  return 1.f - 2.f * __builtin_amdgcn_rcpf(1.f + e);
}

// fp32 (rows,K) -> bf16 (rows,ldp), zero pad cols K..ldp
__global__ void cvt_pad(const float* __restrict__ src, u16* __restrict__ dst,
                        int rows, int K, int ldp) {
  int idx = blockIdx.x * blockDim.x + threadIdx.x;
  int tot = rows * ldp;
  if (idx >= tot) return;
  int c = idx % ldp; int r = idx / ldp;
  float v = (c < K) ? src[(size_t)r * K + c] : 0.f;
  dst[idx] = f2bf(v);
}

// fp32 -> fp8 e4m3, flat
__global__ void cvt_f8(const float* __restrict__ src, u8* __restrict__ dst, int n) {
  int i = blockIdx.x * blockDim.x + threadIdx.x;
  if (i < n) dst[i] = ftofp8(src[i]);
}

// o[j] = bi[j] + (j<512 ? bh[j] : 0)
__global__ void bias_comb(const float* __restrict__ bi, const float* __restrict__ bh,
                          float* __restrict__ o) {
  int j = blockIdx.x * blockDim.x + threadIdx.x;
  if (j >= G3) return;
  o[j] = bi[j] + (j < 512 ? bh[j] : 0.f);
}

// C = A @ B^T + bias; 2 row-tiles x 4 col-tiles per wave.
// Output modes: C fp32 | Cbf bf16 | C8 = packed key-table rows:
//   row = 1024B: bytes[2c]=r-fp8, bytes[2c+1]=z-fp8, bytes[512+2c..]=n-bf16.
__global__ void gemm_bt24(const u16* __restrict__ A, const u16* __restrict__ B,
                          float* __restrict__ C, u16* __restrict__ Cbf,
                          u8* __restrict__ C8,
                          const float* __restrict__ bias,
                          int M, int N, int K, int lda, int ldb, int ldc) {
  int gid = blockIdx.x * blockDim.x + threadIdx.x;
  int wid = gid >> 6, lane = gid & 63;
  int ntg = N >> 6;
  int total = (M >> 5) * ntg;
  if (wid >= total) return;
  int tm = wid / ntg, tg = wid - tm * ntg;
  int rbase = tm << 5, cbase = tg << 6;
  int m = lane & 15, quad = lane >> 4;
  const u16* ap0 = A + (size_t)(rbase + m) * lda + quad * 8;
  const u16* ap1 = ap0 + (size_t)16 * lda;
  const u16* bp0 = B + (size_t)(cbase + m) * ldb + quad * 8;
  f32x4 acc[2][4];
  #pragma unroll
  for (int r = 0; r < 2; ++r)
    #pragma unroll
    for (int c = 0; c < 4; ++c) acc[r][c] = (f32x4){0.f, 0.f, 0.f, 0.f};
  for (int k = 0; k < K; k += 32) {
    bf16x8 a0 = *(const bf16x8*)(ap0 + k);
    bf16x8 a1 = *(const bf16x8*)(ap1 + k);
    #pragma unroll
    for (int c = 0; c < 4; ++c) {
      bf16x8 bv = *(const bf16x8*)(bp0 + (size_t)c * 16 * ldb + k);
      acc[0][c] = __builtin_amdgcn_mfma_f32_16x16x32_bf16(a0, bv, acc[0][c], 0, 0, 0);
      acc[1][c] = __builtin_amdgcn_mfma_f32_16x16x32_bf16(a1, bv, acc[1][c], 0, 0, 0);
    }
  }
  #pragma unroll
  for (int c = 0; c < 4; ++c) {
    int col = cbase + c * 16 + m;
    float bv = bias ? bias[col] : 0.f;
    int g = col >> 8, cc = col & 255;   // gate / in-gate col (C8 mode)
    #pragma unroll
    for (int rt = 0; rt < 2; ++rt) {
      int orow = rbase + rt * 16 + quad * 4;
      #pragma unroll
      for (int i = 0; i < 4; ++i) {
        float v = acc[rt][c][i] + bv;
        if (C8) {
          size_t rb = (size_t)(orow + i) * 1024;
          if (g < 2) C8[rb + 2 * cc + g] = ftofp8(v);
          else *(u16*)&C8[rb + 512 + 2 * cc] = f2bf(v);
        } else if (Cbf) Cbf[(size_t)(orow + i) * ldc + col] = f2bf(v);
        else C[(size_t)(orow + i) * ldc + col] = v;
      }
    }
  }
}

// Async global->LDS 16B gather; aux=0 (policy bits proved irrelevant r8/r10)
#define GLD16(gsrc, ldst)                                                     \
  __builtin_amdgcn_global_load_lds(                                           \
      (const __attribute__((address_space(1))) void*)(gsrc),                  \
      (__attribute__((address_space(3))) void*)(ldst), 16, 0, 0)

// ---- Persistent key-GRU v16 (unchanged R9 winner): W-in-regs, depth-5
// counted-vmcnt gather, 6-slot rotating giL, 6 barriers + 1 drain/step. ----
__global__ __launch_bounds__(1024) void key_gru16(
    const u8* __restrict__ W8f, const u8* __restrict__ W8b,
    const float* __restrict__ nbf, const float* __restrict__ nbb,
    const u8* __restrict__ T8F, const u8* __restrict__ T8B,
    const int* __restrict__ keys_c, const int* __restrict__ keys_r,
    float* __restrict__ h_out) {
  __shared__ __align__(16) u8 hb8[2][80 * 256];  // 2x20 KB ping-pong fp8 h
  __shared__ __align__(16) u8 giL[6 * 16384];    // 96 KB, 6 rotating slots
  __shared__ int tokL[80 * KK];                  // 14 KB token slice
  int b = blockIdx.x;
  int xcd = b & 7, slot0 = b >> 3;
  int bwd = xcd >> 2;
  int j = slot0 * 4 + (xcd & 3);
  int isR = j >> 6;
  int seq0 = (j & 63) * 80;
  const u8* W8 = bwd ? W8b : W8f;
  const u8* T = bwd ? T8B : T8F;
  const int* keys = isR ? keys_r : keys_c;
  const float* nb = bwd ? nbb : nbf;

  int tid = threadIdx.x;
  int w = tid >> 6, lane = tid & 63, m = lane & 15, quad = lane >> 4;
  int c = w * 16 + m;               // this thread's output column (0..255)
  float nbv = nb[512 + c];

  // Token slice: contiguous copy keys[seq0*KK .. (seq0+80)*KK) -> LDS.
  for (int i = tid; i < 80 * KK; i += 1024)
    tokL[i] = keys[seq0 * KK + i];

  // Whh in registers: same 192B per thread for the whole kernel.
  i64 w_r[8], w_z[8], w_n[8];
  {
    const u8* br = W8 + (size_t)(0 * 256 + c) * 256 + quad * 8;
    const u8* bz = W8 + (size_t)(1 * 256 + c) * 256 + quad * 8;
    const u8* bn = W8 + (size_t)(2 * 256 + c) * 256 + quad * 8;
    #pragma unroll
    for (int kc = 0; kc < 8; ++kc) {
      w_r[kc] = *(const i64*)(br + kc * 32);
      w_z[kc] = *(const i64*)(bz + kc * 32);
      w_n[kc] = *(const i64*)(bn + kc * 32);
    }
  }

  // Group g rows [g*16, g*16+16): one 1-row-per-wave GLD16 into slot `sl`.
  auto dma_grp = [&](int tt, int g, int sl) {
    int row = g * 16 + w;
    int tok = tokL[row * KK + tt];                   // wave-uniform ds_read
    const u8* src = T + (size_t)tok * 1024 + lane * 16;
    u8* dst = giL + sl * 16384 + w * 1024;           // + lane*16B by HW
    GLD16(src, dst);
  };

  for (int i = tid * 16; i < 80 * 256; i += 1024 * 16)
    *(i32x4*)&hb8[0][i] = (i32x4){0, 0, 0, 0};
  float h[5][4];
  #pragma unroll
  for (int rt = 0; rt < 5; ++rt)
    #pragma unroll
    for (int i = 0; i < 4; ++i) h[rt][i] = 0.f;

  // Drain ALL prologue vmem so the in-loop per-thread vmcnt stream is exactly
  // the 5 GLD16s/step; tokL + hb8 zeros visible before any dma_grp reads.
  asm volatile("s_waitcnt vmcnt(0) lgkmcnt(0)" ::: "memory");
  __builtin_amdgcn_s_barrier();

  {
    int t0 = bwd ? (KK - 1) : 0;
    #pragma unroll
    for (int g = 0; g < 5; ++g) dma_grp(t0, g, g);   // FIFO: grp0..grp4
  }

  int cc = c >> 3, lo = c & 7;
  int sb = 0;   // slot base: slot(t,g) = (g + sb) % 6; sb(t) = (-t) mod 6

  for (int step = 0; step < KK; ++step) {
    const u8* cur = hb8[step & 1];
    u8* nxt = hb8[(step & 1) ^ 1];
    int tnext = bwd ? (KK - 2 - step) : (step + 1);
    int tclamp = tnext < 0 ? 0 : (tnext > KK - 1 ? KK - 1 : tnext);  // dummy on last step

    #pragma unroll
    for (int rt = 0; rt < 5; ++rt) {
      // ---- GEMM(rt): reads only hb8 rows rt*16..rt*16+15 of cur ----
      f32x4 acc[3];
      #pragma unroll
      for (int g = 0; g < 3; ++g) acc[g] = (f32x4){0.f, 0.f, 0.f, 0.f};
      int arow = rt * 16 + m;
      #pragma unroll
      for (int kc = 0; kc < 8; ++kc) {
        i64 a = *(const i64*)&cur[arow * 256 + (((quad + 4 * kc) ^ (arow & 31)) * 8)];
        acc[0] = __builtin_amdgcn_mfma_f32_16x16x32_fp8_fp8(a, w_r[kc], acc[0], 0, 0, 0);
        acc[1] = __builtin_amdgcn_mfma_f32_16x16x32_fp8_fp8(a, w_z[kc], acc[1], 0, 0, 0);
        acc[2] = __builtin_amdgcn_mfma_f32_16x16x32_fp8_fp8(a, w_n[kc], acc[2], 0, 0, 0);
      }

      // ---- retire exactly group rt(t); keep 4 gathers in flight.
      // Also certifies all waves completed update(rt-1) -> its slot is free.
      asm volatile("s_waitcnt vmcnt(4)" ::: "memory");
      __builtin_amdgcn_s_barrier();
      __builtin_amdgcn_sched_barrier(0);

      // ---- update(rt): reads giL slot(t,rt), writes nxt rows rt ----
      const u16* giU = (const u16*)(giL + ((rt + sb) % 6) * 16384);
      #pragma unroll
      for (int i = 0; i < 4; ++i) {
        int lrow = quad * 4 + i;
        int row = rt * 16 + lrow;
        u16 vrz = giU[lrow * 512 + c];
        f32x2 grz = __builtin_amdgcn_cvt_pk_f32_fp8((int)vrz, false);
        float gn = bf2f(giU[lrow * 512 + 256 + c]);
        float rr = fsig(grz[0] + acc[0][i]);
        float zz = fsig(grz[1] + acc[1][i]);
        float nn = ftanh(gn + rr * (acc[2][i] + nbv));
        float hv = (1.f - zz) * nn + zz * h[rt][i];
        h[rt][i] = hv;
        nxt[row * 256 + ((cc ^ (row & 31)) * 8) + lo] = ftofp8(hv);
      }
      __builtin_amdgcn_sched_barrier(0);  // cap live range per rt-group
      // dma group rt(t+1) into slot(t+1,rt) = slot(t,rt-1) (rt=0 -> free slot)
      dma_grp(tclamp, rt, (rt + sb + 5) % 6);
    }

    // ---- step end: hb8[nxt] writes visible to all waves' next GEMM ----
    asm volatile("s_waitcnt lgkmcnt(0)" ::: "memory");
    __builtin_amdgcn_s_barrier();
    sb = (sb + 5) % 6;
  }

  // Coalesced fp32 epilogue via giL staging (drains dummy DMAs first)
  __syncthreads();
  float* hstage = (float*)giL;
  #pragma unroll
  for (int rt = 0; rt < 5; ++rt)
    #pragma unroll
    for (int i = 0; i < 4; ++i)
      hstage[(rt * 16 + quad * 4 + i) * 256 + c] = h[rt][i];
  __syncthreads();
  size_t rowbase = (size_t)(bwd * NROW + isR * NSEQ + seq0) * 256;
  for (int i = tid * 4; i < 80 * 256; i += 1024 * 4)
    *(f32x4*)&h_out[rowbase + i] = *(const f32x4*)&hstage[i];
}

// Build concat inputs for the main GRU, bf16 padded.
__global__ void build_xe(const float* __restrict__ emb, const int* __restrict__ x1,
                         const int* __restrict__ x2, const float* __restrict__ hk,
                         u16* __restrict__ xe) {
  int idx = blockIdx.x * blockDim.x + threadIdx.x;
  if (idx >= NROW * EHP) return;
  int c = idx % EHP; int rr = idx / EHP;
  int isX2 = rr >= NSEQ;
  int seq = rr - (isX2 ? NSEQ : 0);
  float v;
  if (c < EE) {
    int tok = (isX2 ? x2 : x1)[seq];
    v = emb[(size_t)tok * EE + c];
  } else if (c < EE + HH) {
    int j = c - EE;
    int frow = (isX2 ? NSEQ : 0) + seq;
    v = hk[(size_t)frow * HH + j] + hk[(size_t)(NROW + frow) * HH + j];
  } else {
    v = 0.f;
  }
  xe[idx] = f2bf(v);
}

// ---- Persistent main GRU v7: v4 structure (single __syncthreads, direct
// global gi loads) with 8 WAVES (512 thr), each wave owning 2 col-tiles.
// R10/R11 ledger: gi-latency theory falsified twice (v5 reg-prefetch 1003us,
// v6 LDS-pipeline 795us vs v4's 735us with naive loads) -> v4 already
// covers gi latency under the GEMM; the 2nd barrier costs ~0.4us/step.
// Remaining 4.6us/step >> ~1.5us accounted work. Candidate: wave-stacking
// in lockstep phases (16 waves, 4/SIMD: phase = 4x per-wave issue + chain,
// serialized by the barrier) + 4x redundant hbuf LDS reads (each wave
// reloads the same A-fragments). v7 bisects: 8 waves x 32 cols -> barrier
// participants halve, waves/SIMD 4->2, hbuf LDS traffic halves (A reused
// across the wave's 2 col-tiles), 6 interleaved MFMA chains (better ILP).
// Same math, same order. Flat result => issue-bound.
__global__ __launch_bounds__(512, 1) void main_gru7(
    const u16* __restrict__ Wf, const u16* __restrict__ Wb,
    const float* __restrict__ nbf, const float* __restrict__ nbb,
    const float* __restrict__ Gf, const float* __restrict__ Gb,
    float* __restrict__ sc, u16* __restrict__ scbf,
    float* __restrict__ rvec, u16* __restrict__ rbf) {
  __shared__ __align__(16) u16 hbuf[2][16 * 256];
  int rt = blockIdx.x;
  int q = rt >> 1;
  int bwd = q >> 1, isX2 = q & 1;
  const u16* W = bwd ? Wb : Wf;
  const float* G = bwd ? Gb : Gf;
  const float* nb = bwd ? nbb : nbf;
  int tid = threadIdx.x, w = tid >> 6, lane = tid & 63, m = lane & 15, quad = lane >> 4;
  int c0 = w * 32 + m, c1 = c0 + 16;       // wave w owns cols [w*32, w*32+32)
  float nbv0 = nb[512 + c0], nbv1 = nb[512 + c1];

  const u16* bp[2][3];
  #pragma unroll
  for (int g = 0; g < 3; ++g) {
    bp[0][g] = W + (size_t)(g * 256 + c0) * 256 + quad * 8;
    bp[1][g] = W + (size_t)(g * 256 + c1) * 256 + quad * 8;
  }

  for (int i = tid * 8; i < 16 * 256; i += 512 * 8)
    *(i32x4*)&hbuf[0][i] = (i32x4){0, 0, 0, 0};
  float h[2][4];
  #pragma unroll
  for (int j = 0; j < 2; ++j)
    #pragma unroll
    for (int i = 0; i < 4; ++i) h[j][i] = 0.f;
  __syncthreads();

  for (int step = 0; step < SS; ++step) {
    const u16* cur = hbuf[step & 1];
    u16* nxt = hbuf[(step & 1) ^ 1];
    int s = bwd ? (SS - 1 - step) : step;

    // gi loads issued at phase top; latency covered by the GEMM below.
    float gi[2][3][4];
    #pragma unroll
    for (int i = 0; i < 4; ++i) {
      int bb = ((rt & 1) << 4) + quad * 4 + i;
      size_t girow = ((size_t)(isX2 * NSEQ + bb * SS + s)) * G3;
      #pragma unroll
      for (int g = 0; g < 3; ++g) {
        gi[0][g][i] = G[girow + g * 256 + c0];
        gi[1][g][i] = G[girow + g * 256 + c1];
      }
    }

    f32x4 acc[2][3];
    #pragma unroll
    for (int j = 0; j < 2; ++j)
      #pragma unroll
      for (int g = 0; g < 3; ++g) acc[j][g] = (f32x4){0.f, 0.f, 0.f, 0.f};
    #pragma unroll
    for (int k = 0; k < 8; ++k) {
      bf16x8 a = *(const bf16x8*)&cur[m * 256 + (((quad + 4 * k) ^ m) * 8)];
      #pragma unroll
      for (int j = 0; j < 2; ++j)
        #pragma unroll
        for (int g = 0; g < 3; ++g) {
          bf16x8 bv = *(const bf16x8*)(bp[j][g] + k * 32);
          acc[j][g] = __builtin_amdgcn_mfma_f32_16x16x32_bf16(a, bv, acc[j][g], 0, 0, 0);
        }
    }

    // no barrier: update writes the OTHER buffer
    #pragma unroll
    for (int j = 0; j < 2; ++j) {
      int c = j ? c1 : c0;
      float nbv = j ? nbv1 : nbv0;
      int cc = c >> 3, lo = c & 7;
      #pragma unroll
      for (int i = 0; i < 4; ++i) {
        int row_l = quad * 4 + i;
        float rr = fsig(gi[j][0][i] + acc[j][0][i]);
        float zz = fsig(gi[j][1][i] + acc[j][1][i]);
        float nn = ftanh(gi[j][2][i] + rr * (acc[j][2][i] + nbv));
        float hv = (1.f - zz) * nn + zz * h[j][i];
        h[j][i] = hv;
        nxt[row_l * 256 + ((cc ^ row_l) * 8) + lo] = f2bf(hv);
        if (!isX2) {
          int bb = ((rt & 1) << 4) + row_l;
          size_t o = (size_t)(bb * SS + s) * 512 + (bwd ? 256 : 0) + c;
          sc[o] = hv;
          scbf[o] = f2bf(hv);
        }
      }
    }
    __syncthreads();   // writes visible before next step's GEMM reads
  }
  if (isX2) {   // r = concat(r1f, r1b): finals of x2 fwd/bwd
    #pragma unroll
    for (int j = 0; j < 2; ++j) {
      int c = j ? c1 : c0;
      #pragma unroll
      for (int i = 0; i < 4; ++i) {
        int bb = ((rt & 1) << 4) + quad * 4 + i;
        size_t o = (size_t)bb * 512 + (bwd ? 256 : 0) + c;
        rvec[o] = h[j][i];
        rbf[o] = f2bf(h[j][i]);
      }
    }
  }
}

__global__ void energies_k(const float* __restrict__ a, const float* __restrict__ r,
                           float* __restrict__ e) {
  int gid = blockIdx.x * blockDim.x + threadIdx.x;
  int wid = gid >> 6, lane = gid & 63;
  if (wid >= NSEQ) return;
  int b = wid / SS;
  const float* ar = a + (size_t)wid * 512;
  const float* rr = r + (size_t)b * 512;
  float sum = 0.f;
  for (int i = lane; i < 512; i += 64) sum += ar[i] * rr[i];
  for (int off = 32; off > 0; off >>= 1) sum += __shfl_down(sum, off);
  if (lane == 0) e[wid] = sum;
}

__global__ void softmax_k(const float* __restrict__ e, const float* __restrict__ mask,
                          float* __restrict__ alpha) {
  __shared__ float red[256];
  int b = blockIdx.x, tid = threadIdx.x;
  float v = (tid < SS) ? e[b * SS + tid] : -1e30f;
  red[tid] = v; __syncthreads();
  for (int s = 128; s > 0; s >>= 1) { if (tid < s) red[tid] = fmaxf(red[tid], red[tid + s]); __syncthreads(); }
  float mx = red[0]; __syncthreads();
  float ex = (tid < SS) ? expf(v - mx) : 0.f;
  red[tid] = ex; __syncthreads();
  for (int s = 128; s > 0; s >>= 1) { if (tid < s) red[tid] += red[tid + s]; __syncthreads(); }
  float denom = red[0];
  if (tid < SS) alpha[b * SS + tid] = ex / denom * mask[b * SS + tid];
}

__global__ void cattn_k(const float* __restrict__ alpha, const float* __restrict__ sc,
                        float* __restrict__ c) {
  int b = blockIdx.x, d = threadIdx.x;
  float sum = 0.f;
  for (int s = 0; s < SS; ++s)
    sum += alpha[b * SS + s] * sc[(size_t)(b * SS + s) * 512 + d];
  c[b * 512 + d] = sum;
}

__global__ void final_dot(const float* __restrict__ c, const float* __restrict__ v,
                          const float* __restrict__ bsc, float* __restrict__ out) {
  int b = blockIdx.x, lane = threadIdx.x;
  float s = 0.f;
  for (int i = lane; i < 512; i += 64) s += c[b * 512 + i] * v[b * 512 + i];
  for (int off = 32; off > 0; off >>= 1) s += __shfl_down(s, off);
  if (lane == 0) out[b] = s + bsc[0];
}

extern "C" void kernel_launch(void* const* d_in, const int* in_sizes, int n_in,
                              void* d_out, int out_size, void* d_ws, size_t ws_size,
                              hipStream_t stream) {
  const int*   x1     = (const int*)d_in[0];
  const int*   x2     = (const int*)d_in[1];
  const int*   keys_c = (const int*)d_in[2];
  const int*   keys_r = (const int*)d_in[3];
  const float* x1mask = (const float*)d_in[4];
  const float* emb    = (const float*)d_in[5];
  const float* kWif   = (const float*)d_in[6];
  const float* kWhf   = (const float*)d_in[7];
  const float* kbif   = (const float*)d_in[8];
  const float* kbhf   = (const float*)d_in[9];
  const float* kWib   = (const float*)d_in[10];
  const float* kWhb   = (const float*)d_in[11];
  const float* kbib   = (const float*)d_in[12];
  const float* kbhb   = (const float*)d_in[13];
  const float* eWif   = (const float*)d_in[14];
  const float* eWhf   = (const float*)d_in[15];
  const float* ebif   = (const float*)d_in[16];
  const float* ebhf   = (const float*)d_in[17];
  const float* eWib   = (const float*)d_in[18];
  const float* eWhb   = (const float*)d_in[19];
  const float* ebib   = (const float*)d_in[20];
  const float* ebhb   = (const float*)d_in[21];
  const float* attnW  = (const float*)d_in[22];
  const float* attnb  = (const float*)d_in[23];
  const float* Mw     = (const float*)d_in[24];
  const float* bsc    = (const float*)d_in[25];
  float* out = (float*)d_out;

  char* base = (char*)d_ws;
  size_t off = 0;
  auto take = [&](size_t bytes) -> void* {
    void* p = base + off; off += (bytes + 255) & ~(size_t)255; return p;
  };

  u16* kWif_bf = (u16*)take((size_t)G3 * EP * 2);
  u16* kWib_bf = (u16*)take((size_t)G3 * EP * 2);
  u8*  kW8f    = (u8*)take((size_t)G3 * HH);      // fp8 Whh fwd
  u8*  kW8b    = (u8*)take((size_t)G3 * HH);      // fp8 Whh bwd
  u16* eWif_bf = (u16*)take((size_t)G3 * EHP * 2);
  u16* eWib_bf = (u16*)take((size_t)G3 * EHP * 2);
  u16* eWhf_bf = (u16*)take((size_t)G3 * HH * 2);
  u16* eWhb_bf = (u16*)take((size_t)G3 * HH * 2);
  u16* attnW_bf = (u16*)take((size_t)512 * 512 * 2);
  u16* M_bf    = (u16*)take((size_t)512 * 512 * 2);
  u16* xe_bf   = (u16*)take((size_t)NROW * EHP * 2);
  float* cb_kf = (float*)take(G3 * 4);
  float* cb_kb = (float*)take(G3 * 4);
  float* cb_ef = (float*)take(G3 * 4);
  float* cb_eb = (float*)take(G3 * 4);
  float* h_key = (float*)take((size_t)NKEY * HH * 4);   // persistent: outlives overlay

  size_t pbase = off;
  u16* emb_bf = (u16*)take((size_t)VV * EP * 2);
  u8*  T8F    = (u8*)take((size_t)VV * 1024);   // packed key-table fwd
  u8*  T8B    = (u8*)take((size_t)VV * 1024);   // packed key-table bwd

  off = pbase;
  float* Gf = (float*)take((size_t)NROW * G3 * 4);
  float* Gb = (float*)take((size_t)NROW * G3 * 4);
  float* sc = (float*)take((size_t)NSEQ * 512 * 4);
  u16*   sc_bf = (u16*)take((size_t)NSEQ * 512 * 2);
  float* rvec = (float*)take((size_t)BB * 512 * 4);
  u16*   r_bf = (u16*)take((size_t)BB * 512 * 2);
  float* abuf = (float*)take((size_t)NSEQ * 512 * 4);
  float* energ = (float*)take((size_t)BB * SS * 4);
  float* alpha = (float*)take((size_t)BB * SS * 4);
  float* c_attn = (float*)take((size_t)BB * 512 * 4);
  float* vbuf = (float*)take((size_t)BB * 512 * 4);

  auto cvt = [&](const float* s, u16* d, int rows, int K, int ldp) {
    int tot = rows * ldp;
    cvt_pad<<<(tot + 255) / 256, 256, 0, stream>>>(s, d, rows, K, ldp);
  };
  auto gemm = [&](const u16* A, const u16* B, float* C, u16* Cbf, u8* C8,
                  const float* bias,
                  int M, int N, int K, int lda, int ldb, int ldc) {
    long long waves = (long long)(M >> 5) * (N >> 6);
    int blocks = (int)((waves * 64 + 255) / 256);
    gemm_bt24<<<blocks, 256, 0, stream>>>(A, B, C, Cbf, C8, bias, M, N, K, lda, ldb, ldc);
  };

  cvt(emb, emb_bf, VV, EE, EP);
  cvt(kWif, kWif_bf, G3, EE, EP);
  cvt(kWib, kWib_bf, G3, EE, EP);
  cvt_f8<<<(G3 * HH + 255) / 256, 256, 0, stream>>>(kWhf, kW8f, G3 * HH);
  cvt_f8<<<(G3 * HH + 255) / 256, 256, 0, stream>>>(kWhb, kW8b, G3 * HH);
  cvt(eWif, eWif_bf, G3, 556, EHP);
  cvt(eWib, eWib_bf, G3, 556, EHP);
  cvt(eWhf, eWhf_bf, G3, HH, HH);
  cvt(eWhb, eWhb_bf, G3, HH, HH);
  cvt(attnW, attnW_bf, 512, 512, 512);
  cvt(Mw, M_bf, 512, 512, 512);
  bias_comb<<<3, 256, 0, stream>>>(kbif, kbhf, cb_kf);
  bias_comb<<<3, 256, 0, stream>>>(kbib, kbhb, cb_kb);
  bias_comb<<<3, 256, 0, stream>>>(ebif, ebhf, cb_ef);
  bias_comb<<<3, 256, 0, stream>>>(ebib, ebhb, cb_eb);

  gemm(emb_bf, kWif_bf, nullptr, nullptr, T8F, cb_kf, VV, G3, EP, EP, EP, G3);
  gemm(emb_bf, kWib_bf, nullptr, nullptr, T8B, cb_kb, VV, G3, EP, EP, EP, G3);

  key_gru16<<<256, 1024, 0, stream>>>(kW8f, kW8b, kbhf, kbhb,
                                      T8F, T8B, keys_c, keys_r, h_key);

  build_xe<<<(NROW * EHP + 255) / 256, 256, 0, stream>>>(emb, x1, x2, h_key, xe_bf);

  gemm(xe_bf, eWif_bf, Gf, nullptr, nullptr, cb_ef, NROW, G3, EHP, EHP, EHP, G3);
  gemm(xe_bf, eWib_bf, Gb, nullptr, nullptr, cb_eb, NROW, G3, EHP, EHP, EHP, G3);

  main_gru7<<<8, 512, 0, stream>>>(eWhf_bf, eWhb_bf, ebhf, ebhb,
                                   Gf, Gb, sc, sc_bf, rvec, r_bf);

  gemm(sc_bf, attnW_bf, abuf, nullptr, nullptr, attnb, NSEQ, 512, 512, 512, 512, 512);
  energies_k<<<(NSEQ * 64 + 255) / 256, 256, 0, stream>>>(abuf, rvec, energ);
  softmax_k<<<BB, 256, 0, stream>>>(energ, x1mask, alpha);
  cattn_k<<<BB, 512, 0, stream>>>(alpha, sc, c_attn);
  gemm(r_bf, M_bf, vbuf, nullptr, nullptr, nullptr, BB, 512, 512, 512, 512, 512);
  final_dot<<<BB, 64, 0, stream>>>(c_attn, vbuf, bsc, out);
}